// Round 6
// baseline (186.923 us; speedup 1.0000x reference)
//
#include <hip/hip_runtime.h>

typedef float v4f __attribute__((ext_vector_type(4)));
typedef short v8s __attribute__((ext_vector_type(8)));
typedef v8s v8s_a __attribute__((may_alias));

#define PBLOCKS 128
#define NEG 0.2f
#define XSLOT 544   // f32 slot stride (16 slots); node stride 68 f32 (272 B, 16B-aligned)
#define XNODE 68

static __device__ __forceinline__ unsigned short f2bf(float f) {
  union { float f; unsigned u; } x; x.f = f;
  return (unsigned short)((x.u + 0x7FFFu + ((x.u >> 16) & 1u)) >> 16);  // RNE
}
// v = hi + lo (both bf16), |err| ~ 2^-17 * |v|
static __device__ __forceinline__ void split2(float v, short& hi, short& lo) {
  union { float f; unsigned u; } x; x.f = v;
  const unsigned r = (x.u + 0x7FFFu + ((x.u >> 16) & 1u)) & 0xFFFF0000u;
  hi = (short)(r >> 16);
  union { unsigned u; float f; } h; h.u = r;
  lo = (short)f2bf(v - h.f);
}
static __device__ __forceinline__ void load_split8(const float* p, v8s& hi, v8s& lo) {
#pragma unroll
  for (int j = 0; j < 8; ++j) { short a, b; split2(p[j], a, b); hi[j] = a; lo[j] = b; }
}
__device__ __forceinline__ void fma4(float4& d, float a, const float4 b) {
  d.x = fmaf(a, b.x, d.x); d.y = fmaf(a, b.y, d.y);
  d.z = fmaf(a, b.z, d.z); d.w = fmaf(a, b.w, d.w);
}
__device__ __forceinline__ float4 leaky4(float4 v) {
  v.x = fmaxf(v.x, NEG * v.x); v.y = fmaxf(v.y, NEG * v.y);
  v.z = fmaxf(v.z, NEG * v.z); v.w = fmaxf(v.w, NEG * v.w);
  return v;
}

// Hybrid, bf16x3-precision GEMMs.
// VALU (f32) for adjacency/x1/x2 (K=8); MFMA for t/m/s (K=64) with
// A = ahi+alo, B = bhi+blo, product = alo@bhi + ahi@blo + ahi@bhi.
// Activations live in LDS as f32 (split at read). Structure == round 5 (validated).
// Block = 256 thr = 4 waves = 16 slots; blocks 0..127 p-path, rest n-path.
// A/B frag: lane l elem j <-> k = 8*(l>>4)+j ; C/D [m89]: row=4*(l>>4)+reg, col=l&15.
__global__ __launch_bounds__(256, 1)
void enc_hyb(const float* __restrict__ adj, const float* __restrict__ noise,
             const float* __restrict__ W1p, const float* __restrict__ b1p,
             const float* __restrict__ W2p, const float* __restrict__ b2p,
             const float* __restrict__ Wmp, const float* __restrict__ bmp,
             const float* __restrict__ gmp, const float* __restrict__ betamp,
             const float* __restrict__ Wsp, const float* __restrict__ bsp,
             const float* __restrict__ gsp, const float* __restrict__ betasp,
             const float* __restrict__ W1n, const float* __restrict__ b1n,
             const float* __restrict__ W2n, const float* __restrict__ b2n,
             const float* __restrict__ Wmn, const float* __restrict__ bmn,
             const float* __restrict__ gmn, const float* __restrict__ betamn,
             const float* __restrict__ Wsn, const float* __restrict__ bsn,
             const float* __restrict__ gsn, const float* __restrict__ betasn,
             float* __restrict__ out)
{
  __shared__ __align__(16) short fragWhi[24 * 512];  // W2|Wm|Ws hi-plane
  __shared__ __align__(16) short fragWlo[24 * 512];  // lo-plane
  __shared__ __align__(16) float Abuf[16 * 72];      // normalized adjacency
  __shared__ __align__(16) float XbF[16 * XSLOT];    // x1 then x2, f32
  __shared__ __align__(16) float TbF[16 * XSLOT];    // t, f32

  const int tid = threadIdx.x;
  const int l = tid & 63;
  const int w = tid >> 6;
  const int c = l & 15;
  const int g = l >> 4;

  const bool isp = (blockIdx.x < PBLOCKS);
  const int bip = isp ? (int)blockIdx.x : ((int)blockIdx.x - PBLOCKS);

  const float* W1 = isp ? W1p : W1n;   const float* B1 = isp ? b1p : b1n;
  const float* W2 = isp ? W2p : W2n;   const float* B2 = isp ? b2p : b2n;
  const float* WM = isp ? Wmp : Wmn;   const float* BM = isp ? bmp : bmn;
  const float* GM = isp ? gmp : gmn;   const float* BEM = isp ? betamp : betamn;
  const float* WS = isp ? Wsp : Wsn;   const float* BS = isp ? bsp : bsn;
  const float* GS = isp ? gsp : gsn;   const float* BES = isp ? betasp : betasn;

  // ---- stage weight B-fragments (hi/lo): f 0..7=W2, 8..15=Wm, 16..23=Ws ----
  // frag f = mat*8 + kt*4 + nt : elem j at k = kt*32 + 8g + j, col (nt*16 + c)
  for (int f = w; f < 24; f += 4) {
    const float* M = (f < 8) ? W2 : ((f < 16) ? WM : WS);
    const int r = f & 7;
    const int kt = r >> 2;
    const int cn = (r & 3) * 16 + c;
#pragma unroll
    for (int j = 0; j < 8; ++j) {
      short h, s2;
      split2(M[(kt * 32 + g * 8 + j) * 64 + cn], h, s2);
      fragWhi[f * 512 + l * 8 + j] = h;
      fragWlo[f * 512 + l * 8 + j] = s2;
    }
  }

  // ---- pair instance indices (wave-uniform per P) ----
  int instA[2], instB[2];
#pragma unroll
  for (int P = 0; P < 2; ++P) {
    const int gi = bip * 8 + w * 2 + P;
    if (isp) {
      instA[P] = gi * 64;            // b=2*gi,   c=0
      instB[P] = gi * 64 + 32;       // b=2*gi+1, c=0
    } else {
      const unsigned n0 = 2u * (unsigned)gi;
      const unsigned n1 = n0 + 1u;
      const unsigned q0 = n0 / 31u;
      const unsigned q1 = n1 / 31u;
      instA[P] = (int)(q0 * 32u + 1u + (n0 - q0 * 31u));
      instB[P] = (int)(q1 * 32u + 1u + (n1 - q1 * 31u));
    }
  }
  const int s_mine = w * 4 + g;
  const int inst_mine = (s_mine & 1) ? instB[(s_mine >> 1) & 1]
                                     : instA[(s_mine >> 1) & 1];

  // ---- stage raw adjacency: lane c covers float4 #c of its slot ----
  {
    float4 a = ((const float4*)adj)[inst_mine * 16 + c];
    *(float4*)&Abuf[s_mine * 72 + c * 4] = a;
  }
  __syncthreads();

  // ---- row-normalize: lanes c<8 own one row each ----
  if (c < 8) {
    float4 r0 = *(const float4*)&Abuf[s_mine * 72 + c * 8];
    float4 r1 = *(const float4*)&Abuf[s_mine * 72 + c * 8 + 4];
    float s = r0.x + r0.y + r0.z + r0.w + r1.x + r1.y + r1.z + r1.w;
    s = (s == 0.0f) ? 1.0f : s;
    const float rinv = 1.0f / s;
    r0.x *= rinv; r0.y *= rinv; r0.z *= rinv; r0.w *= rinv;
    r1.x *= rinv; r1.y *= rinv; r1.z *= rinv; r1.w *= rinv;
    *(float4*)&Abuf[s_mine * 72 + c * 8]     = r0;
    *(float4*)&Abuf[s_mine * 72 + c * 8 + 4] = r1;
  }
  __syncthreads();

  // ---- x1 = leaky(A @ W1 + b1), f32 VALU -> XbF [slot][node(68)][feat] ----
  {
    const float4* W1f = (const float4*)W1;
    const float4* B1f = (const float4*)B1;
    float4 w1r[8];
#pragma unroll
    for (int k = 0; k < 8; ++k) w1r[k] = W1f[k * 16 + c];
    const float4 b14 = B1f[c];
#pragma unroll
    for (int i = 0; i < 8; ++i) {
      float4 a0 = *(const float4*)&Abuf[s_mine * 72 + i * 8];
      float4 a1 = *(const float4*)&Abuf[s_mine * 72 + i * 8 + 4];
      float4 acc = b14;
      fma4(acc, a0.x, w1r[0]); fma4(acc, a0.y, w1r[1]);
      fma4(acc, a0.z, w1r[2]); fma4(acc, a0.w, w1r[3]);
      fma4(acc, a1.x, w1r[4]); fma4(acc, a1.y, w1r[5]);
      fma4(acc, a1.z, w1r[6]); fma4(acc, a1.w, w1r[7]);
      acc = leaky4(acc);
      *(float4*)&XbF[s_mine * XSLOT + i * XNODE + c * 4] = acc;
    }
  }
  __syncthreads();

  // ---- t = x1 @ W2 via bf16x3 MFMA; scatter C-frags -> TbF (f32) ----
#pragma unroll
  for (int P = 0; P < 2; ++P) {
    const int slotA = w * 4 + P * 2 + (c >> 3);  // A row c -> slot/node
    const int node = c & 7;
    v8s ah0, al0, ah1, al1;
    load_split8(&XbF[slotA * XSLOT + node * XNODE + g * 8], ah0, al0);
    load_split8(&XbF[slotA * XSLOT + node * XNODE + 32 + g * 8], ah1, al1);
#pragma unroll
    for (int nt = 0; nt < 4; ++nt) {
      const v8s bh0 = *(const v8s_a*)&fragWhi[(0 + nt) * 512 + l * 8];
      const v8s bl0 = *(const v8s_a*)&fragWlo[(0 + nt) * 512 + l * 8];
      const v8s bh1 = *(const v8s_a*)&fragWhi[(4 + nt) * 512 + l * 8];
      const v8s bl1 = *(const v8s_a*)&fragWlo[(4 + nt) * 512 + l * 8];
      v4f acc = { 0.0f, 0.0f, 0.0f, 0.0f };
      acc = __builtin_amdgcn_mfma_f32_16x16x32_bf16(al0, bh0, acc, 0, 0, 0);
      acc = __builtin_amdgcn_mfma_f32_16x16x32_bf16(ah0, bl0, acc, 0, 0, 0);
      acc = __builtin_amdgcn_mfma_f32_16x16x32_bf16(ah0, bh0, acc, 0, 0, 0);
      acc = __builtin_amdgcn_mfma_f32_16x16x32_bf16(al1, bh1, acc, 0, 0, 0);
      acc = __builtin_amdgcn_mfma_f32_16x16x32_bf16(ah1, bl1, acc, 0, 0, 0);
      acc = __builtin_amdgcn_mfma_f32_16x16x32_bf16(ah1, bh1, acc, 0, 0, 0);
#pragma unroll
      for (int q = 0; q < 4; ++q) {
        const int rr = 4 * g + q;                 // C row in pair tile
        const int slotC = w * 4 + P * 2 + (rr >> 3);
        TbF[slotC * XSLOT + (rr & 7) * XNODE + nt * 16 + c] = acc[q];
      }
    }
  }
  __syncthreads();

  // ---- x2 = leaky(A @ t + b2), f32 VALU -> XbF (overwrite x1) ----
  {
    const float4* B2f = (const float4*)B2;
    const float4 b24 = B2f[c];
#pragma unroll
    for (int i = 0; i < 8; ++i) {
      float4 a0 = *(const float4*)&Abuf[s_mine * 72 + i * 8];
      float4 a1 = *(const float4*)&Abuf[s_mine * 72 + i * 8 + 4];
      float ar[8];
      ar[0] = a0.x; ar[1] = a0.y; ar[2] = a0.z; ar[3] = a0.w;
      ar[4] = a1.x; ar[5] = a1.y; ar[6] = a1.z; ar[7] = a1.w;
      float4 acc = b24;
#pragma unroll
      for (int kk = 0; kk < 8; ++kk) {
        const float4 trow = *(const float4*)&TbF[s_mine * XSLOT + kk * XNODE + c * 4];
        fma4(acc, ar[kk], trow);
      }
      acc = leaky4(acc);
      *(float4*)&XbF[s_mine * XSLOT + i * XNODE + c * 4] = acc;
    }
  }
  __syncthreads();

  // ---- per-lane epilogue constants ----
  float bmv[4], bsv[4], gmv[4], bemv[4], gsv[4], besv[4], nz[4][4];
#pragma unroll
  for (int nt = 0; nt < 4; ++nt) {
    const int cn = nt * 16 + c;
    bmv[nt] = BM[cn]; bsv[nt] = BS[cn];
    gmv[nt] = GM[cn]; bemv[nt] = BEM[cn];
    gsv[nt] = GS[cn]; besv[nt] = BES[cn];
#pragma unroll
    for (int q = 0; q < 4; ++q)
      nz[nt][q] = noise[((g & 1) * 4 + q) * 64 + cn];
  }

  // ---- m,s = x2 @ {Wm,Ws} + bias via bf16x3 MFMA; BN + reparam ----
#pragma unroll
  for (int P = 0; P < 2; ++P) {
    const int slotA = w * 4 + P * 2 + (c >> 3);
    const int node = c & 7;
    v8s ah0, al0, ah1, al1;
    load_split8(&XbF[slotA * XSLOT + node * XNODE + g * 8], ah0, al0);
    load_split8(&XbF[slotA * XSLOT + node * XNODE + 32 + g * 8], ah1, al1);
    const int obase0 = ((g >> 1) ? instB[P] : instA[P]) * 512 + (g & 1) * 256;
#pragma unroll
    for (int nt = 0; nt < 4; ++nt) {
      v4f mc = { bmv[nt], bmv[nt], bmv[nt], bmv[nt] };
      {
        const v8s bh0 = *(const v8s_a*)&fragWhi[(8 + nt) * 512 + l * 8];
        const v8s bl0 = *(const v8s_a*)&fragWlo[(8 + nt) * 512 + l * 8];
        const v8s bh1 = *(const v8s_a*)&fragWhi[(12 + nt) * 512 + l * 8];
        const v8s bl1 = *(const v8s_a*)&fragWlo[(12 + nt) * 512 + l * 8];
        mc = __builtin_amdgcn_mfma_f32_16x16x32_bf16(al0, bh0, mc, 0, 0, 0);
        mc = __builtin_amdgcn_mfma_f32_16x16x32_bf16(ah0, bl0, mc, 0, 0, 0);
        mc = __builtin_amdgcn_mfma_f32_16x16x32_bf16(ah0, bh0, mc, 0, 0, 0);
        mc = __builtin_amdgcn_mfma_f32_16x16x32_bf16(al1, bh1, mc, 0, 0, 0);
        mc = __builtin_amdgcn_mfma_f32_16x16x32_bf16(ah1, bl1, mc, 0, 0, 0);
        mc = __builtin_amdgcn_mfma_f32_16x16x32_bf16(ah1, bh1, mc, 0, 0, 0);
      }
      v4f sc = { bsv[nt], bsv[nt], bsv[nt], bsv[nt] };
      {
        const v8s bh0 = *(const v8s_a*)&fragWhi[(16 + nt) * 512 + l * 8];
        const v8s bl0 = *(const v8s_a*)&fragWlo[(16 + nt) * 512 + l * 8];
        const v8s bh1 = *(const v8s_a*)&fragWhi[(20 + nt) * 512 + l * 8];
        const v8s bl1 = *(const v8s_a*)&fragWlo[(20 + nt) * 512 + l * 8];
        sc = __builtin_amdgcn_mfma_f32_16x16x32_bf16(al0, bh0, sc, 0, 0, 0);
        sc = __builtin_amdgcn_mfma_f32_16x16x32_bf16(ah0, bl0, sc, 0, 0, 0);
        sc = __builtin_amdgcn_mfma_f32_16x16x32_bf16(ah0, bh0, sc, 0, 0, 0);
        sc = __builtin_amdgcn_mfma_f32_16x16x32_bf16(al1, bh1, sc, 0, 0, 0);
        sc = __builtin_amdgcn_mfma_f32_16x16x32_bf16(ah1, bl1, sc, 0, 0, 0);
        sc = __builtin_amdgcn_mfma_f32_16x16x32_bf16(ah1, bh1, sc, 0, 0, 0);
      }

      float smm = (mc[0] + mc[1]) + (mc[2] + mc[3]);
      smm += __shfl_xor(smm, 16);
      const float mum = smm * 0.125f;
      float sms = (sc[0] + sc[1]) + (sc[2] + sc[3]);
      sms += __shfl_xor(sms, 16);
      const float mus = sms * 0.125f;
      float vm = 0.0f, vs = 0.0f;
#pragma unroll
      for (int q = 0; q < 4; ++q) {
        const float dm = mc[q] - mum; vm = fmaf(dm, dm, vm);
        const float ds = sc[q] - mus; vs = fmaf(ds, ds, vs);
      }
      vm += __shfl_xor(vm, 16);
      vs += __shfl_xor(vs, 16);
      const float sclm = gmv[nt] * rsqrtf(vm * 0.125f + 1e-5f);
      const float scls = gsv[nt] * rsqrtf(vs * 0.125f + 1e-5f);
      const int oc = obase0 + nt * 16 + c;
#pragma unroll
      for (int q = 0; q < 4; ++q) {
        const float lv = (sc[q] - mus) * scls + besv[nt];
        const float ex = exp2f(0.72134752044448f * lv);  // exp(0.5*lv)
        out[oc + q * 64] = (mc[q] - mum) * sclm + bemv[nt] + ex * nz[nt][q];
      }
    }
  }
}

extern "C" void kernel_launch(void* const* d_in, const int* in_sizes, int n_in,
                              void* d_out, int out_size, void* d_ws, size_t ws_size,
                              hipStream_t stream) {
  const float* adj   = (const float*)d_in[0];
  const float* noise = (const float*)d_in[1];
  const float* W1p = (const float*)d_in[2];  const float* b1p = (const float*)d_in[3];
  const float* W2p = (const float*)d_in[4];  const float* b2p = (const float*)d_in[5];
  const float* Wmp = (const float*)d_in[6];  const float* bmp = (const float*)d_in[7];
  const float* gmp = (const float*)d_in[8];  const float* betamp = (const float*)d_in[9];
  const float* Wsp = (const float*)d_in[10]; const float* bsp = (const float*)d_in[11];
  const float* gsp = (const float*)d_in[12]; const float* betasp = (const float*)d_in[13];
  const float* W1n = (const float*)d_in[14]; const float* b1n = (const float*)d_in[15];
  const float* W2n = (const float*)d_in[16]; const float* b2n = (const float*)d_in[17];
  const float* Wmn = (const float*)d_in[18]; const float* bmn = (const float*)d_in[19];
  const float* gmn = (const float*)d_in[20]; const float* betamn = (const float*)d_in[21];
  const float* Wsn = (const float*)d_in[22]; const float* bsn = (const float*)d_in[23];
  const float* gsn = (const float*)d_in[24]; const float* betasn = (const float*)d_in[25];

  // 128 p-blocks (1024 pairs) + 3968 n-blocks (31744 pairs) = 4096 blocks
  enc_hyb<<<4096, 256, 0, stream>>>(
      adj, noise,
      W1p, b1p, W2p, b2p, Wmp, bmp, gmp, betamp, Wsp, bsp, gsp, betasp,
      W1n, b1n, W2n, b2n, Wmn, bmn, gmn, betamn, Wsn, bsn, gsn, betasn,
      (float*)d_out);
}